// Round 10
// baseline (38.243 us; speedup 1.0000x reference)
//
#include <hip/hip_runtime.h>

// FoveatedSamplingConv2d — bf16 MFMA implicit GEMM with LDS-staged halo.
// Per block (one h row, 256 px): stage the 69 needed rows (3 ch x 23 distinct
// dy) x 672B into LDS once via global_load_lds, then serve all 384 taps from
// LDS (3x ds_read_b32 + 2x alignbit per tap handles 2B-unaligned windows).
// Single padded bf16 copy (no shifted replicas), XCD-aligned prep, NT stores.

#define HH 256
#define WW 256
#define INC 3
#define OC 64
#define KS 11
#define BB 4
#define NKC 12           // K chunks of 32 (3*128/32)
#define PH 326           // 256 + 2*35
#define PW 512           // padded row stride (elements)
#define PAD 35
#define NDY 23           // distinct dy values
#define NROW 69          // 3 channels * NDY
#define ROWB 672         // staged bytes per LDS row (42*16, covers 336 px)
#define ROWU16 336

typedef __attribute__((ext_vector_type(4))) float f32x4;
typedef __attribute__((ext_vector_type(8))) short s16x8;
typedef unsigned int u32;
typedef unsigned short u16;

static __device__ const int dyv[NDY] = {
    -35, -28, -21, -15, -14, -10, -7, -6, -5, -3, -1,
      0,   1,   3,   5,   6,   7, 10, 14, 15, 21, 28, 35};

static __device__ __forceinline__ u16 f2bf(float f) {
    u32 u = __builtin_bit_cast(u32, f);
    u32 r = (u + 0x7FFFu + ((u >> 16) & 1u)) >> 16;   // RTNE (finite data)
    return (u16)r;
}

// ---- fused prep -----------------------------------------------------------
// blocks [0,96): W fragments (bf16 A-fragment order).
// blocks [96,96+1960): single padded copy, XCD-aligned with main's readers:
//   XCD k = pb&7 = 2*b + (py>=163).
__global__ void __launch_bounds__(256)
prep_fused(const float* __restrict__ x, const float* __restrict__ w,
           u16* __restrict__ xs, u16* __restrict__ wf) {
    const int tid = threadIdx.x;
    if (blockIdx.x < 96) {
        int i = blockIdx.x * 256 + tid;              // 0..24575
        int j    = i & 7;
        int lane = (i >> 3) & 63;
        int ot   = (i >> 9) & 3;
        int kc   = i >> 11;
        int o  = ot * 16 + (lane & 15);
        int k  = kc * 32 + ((lane >> 4) << 3) + j;
        int c  = k >> 7;
        int tt = k & 127;
        float val = 0.f;
        if (tt < 121) {
            int ky = tt / 11, kx = tt % 11;
            val = w[((o * INC + c) * KS + ky) * KS + kx];
        }
        wf[i] = f2bf(val);
    } else {
        const int pb = blockIdx.x - 96;              // 0..1959
        const int k  = pb & 7;                       // target XCD
        const int i  = pb >> 3;                      // 0..244
        const int r  = i * 2 + (tid >> 7);           // 0..489
        if (r < 3 * 163) {
            const int c   = r / 163;
            const int pz  = r - c * 163;
            const int py  = (k & 1) * 163 + pz;      // 0..325
            const int b   = k >> 1;
            const int px0 = (tid & 127) * 4;
            const int sy  = min(max(py - PAD, 0), HH - 1);
            const float* src = x + (((size_t)b * INC + c) * HH + sy) * WW;
            ushort4 o4;
            int s0 = min(max(px0 + 0 - PAD, 0), WW - 1);
            int s1 = min(max(px0 + 1 - PAD, 0), WW - 1);
            int s2 = min(max(px0 + 2 - PAD, 0), WW - 1);
            int s3 = min(max(px0 + 3 - PAD, 0), WW - 1);
            o4.x = f2bf(src[s0]); o4.y = f2bf(src[s1]);
            o4.z = f2bf(src[s2]); o4.w = f2bf(src[s3]);
            *(ushort4*)&xs[(((size_t)b * INC + c) * PH + py) * PW + px0] = o4;
        }
    }
}

// ---- main: 4 waves; wave = 64 px (4 MFMA tiles); taps served from LDS -----
__global__ void __launch_bounds__(256, 3)
fov_lds(const u16* __restrict__ xs, const u16* __restrict__ wf,
        const float* __restrict__ bias, float* __restrict__ out) {
    __shared__ __align__(16) u16 sdata[NROW * ROWU16];   // 46368 B
    __shared__ u32 offL[NKC * 32];                       //  1536 B

    const int tid  = threadIdx.x;
    const int lane = tid & 63;
    const int wv   = tid >> 6;
    // bijective XCD swizzle: XCD = bid&7 = 2*b + (h>=128)
    const int obid = (blockIdx.x & 7) * 128 + (blockIdx.x >> 3);
    const int b = obid >> 8;
    const int h = obid & 255;

    // per-tap LDS byte offsets: slot row * ROWB + (PAD+dx)*2
    for (int t = tid; t < NKC * 32; t += 256) {
        int c = t >> 7, tt = t & 127;
        u32 v = 0;
        if (tt < 121) {
            int ky = tt / 11, kx = tt - (tt / 11) * 11;
            int ay = ky - 5, ax = kx - 5;
            int d = max(abs(ay), abs(ax));
            int sc = (d <= 1) ? 1 : (d == 2 ? 3 : (d == 3 ? 5 : 7));
            int dy = ay * sc, dx = ax * sc;
            int di = 0;
#pragma unroll
            for (int s = 0; s < NDY; ++s) if (dyv[s] == dy) di = s;
            v = (u32)((c * NDY + di) * ROWB + (PAD + dx) * 2);
        }
        offL[t] = v;
    }

    // stage 69 halo rows (672 B each) into LDS via global_load_lds width-16
    for (int ri = wv; ri < NROW; ri += 4) {
        int c  = (ri >= 2 * NDY) ? 2 : (ri >= NDY ? 1 : 0);
        int di = ri - c * NDY;
        int py = h + PAD + dyv[di];                  // 0..325, in range
        const char* src = (const char*)(xs + (((size_t)b * INC + c) * PH + py) * PW);
        if (lane < ROWB / 16) {
            __builtin_amdgcn_global_load_lds(
                (const __attribute__((address_space(1))) void*)(src + lane * 16),
                (__attribute__((address_space(3))) void*)&sdata[ri * ROWU16],
                16, 0, 0);
        }
    }
    __syncthreads();   // drains vmcnt: staged data + offL visible

    const int g16 = lane & 15;         // pixel group: px = wv*64 + 4*g16 + T
    const int kg  = lane >> 4;         // tap group within chunk
    const u32 lane_base = (u32)((wv * 64 + 4 * g16) * 2);
    const u32* s32 = (const u32*)sdata;
    const s16x8* wbase = (const s16x8*)wf;

    f32x4 acc[4][4];                   // [tile T][o-block]
#pragma unroll
    for (int T = 0; T < 4; ++T)
#pragma unroll
        for (int ob = 0; ob < 4; ++ob) acc[T][ob] = (f32x4){0, 0, 0, 0};

    s16x8 A[2][4];                     // weight double-buffer (global, L2-hot)
    {
        const s16x8* wp = wbase + lane;
        A[0][0] = wp[0]; A[0][1] = wp[64]; A[0][2] = wp[128]; A[0][3] = wp[192];
    }

#pragma unroll
    for (int kc = 0; kc < NKC; ++kc) {
        const int cur = kc & 1;
        const int nxt = cur ^ 1;
        if (kc + 1 < NKC) {            // prefetch next weights
            const s16x8* wp = wbase + (((kc + 1) << 8) + lane);
            A[nxt][0] = wp[0];   A[nxt][1] = wp[64];
            A[nxt][2] = wp[128]; A[nxt][3] = wp[192];
        }
        const uint4* lp = (const uint4*)&offL[kc * 32 + kg * 8];
        const uint4 oA = lp[0], oB = lp[1];
        const u32 offs[8] = {oA.x, oA.y, oA.z, oA.w, oB.x, oB.y, oB.z, oB.w};
        u32 lo[8], hi[8];
#pragma unroll
        for (int j = 0; j < 8; ++j) {  // 8 taps, 4 px each, from LDS
            u32 addr = lane_base + offs[j];
            u32 i0 = addr >> 2;
            u32 sh = (addr & 2) << 3;  // 0 or 16
            u32 w0 = s32[i0], w1 = s32[i0 + 1], w2 = s32[i0 + 2];
            lo[j] = __builtin_amdgcn_alignbit(w1, w0, sh);   // px {0,1}
            hi[j] = __builtin_amdgcn_alignbit(w2, w1, sh);   // px {2,3}
        }
        __builtin_amdgcn_s_setprio(1);
#pragma unroll
        for (int T = 0; T < 4; ++T) {
            const u32 sel = (T & 1) ? 0x07060302u : 0x05040100u;
            const bool up = (T >> 1) != 0;
            union { u32 u[4]; s16x8 v; } bu;
            bu.u[0] = __builtin_amdgcn_perm(up ? hi[1] : lo[1], up ? hi[0] : lo[0], sel);
            bu.u[1] = __builtin_amdgcn_perm(up ? hi[3] : lo[3], up ? hi[2] : lo[2], sel);
            bu.u[2] = __builtin_amdgcn_perm(up ? hi[5] : lo[5], up ? hi[4] : lo[4], sel);
            bu.u[3] = __builtin_amdgcn_perm(up ? hi[7] : lo[7], up ? hi[6] : lo[6], sel);

            acc[T][0] = __builtin_amdgcn_mfma_f32_16x16x32_bf16(A[cur][0], bu.v, acc[T][0], 0, 0, 0);
            acc[T][1] = __builtin_amdgcn_mfma_f32_16x16x32_bf16(A[cur][1], bu.v, acc[T][1], 0, 0, 0);
            acc[T][2] = __builtin_amdgcn_mfma_f32_16x16x32_bf16(A[cur][2], bu.v, acc[T][2], 0, 0, 0);
            acc[T][3] = __builtin_amdgcn_mfma_f32_16x16x32_bf16(A[cur][3], bu.v, acc[T][3], 0, 0, 0);
        }
        __builtin_amdgcn_s_setprio(0);
    }

    // D: col = lane&15 = pixel-group; row = kg*4 + r = o within 16-block.
    const int orow = kg << 2;
    const float4* bp = (const float4*)bias;
#pragma unroll
    for (int ob = 0; ob < 4; ++ob) {
        const float4 bb = bp[ob * 4 + kg];
        const float bv[4] = {bb.x, bb.y, bb.z, bb.w};
#pragma unroll
        for (int r = 0; r < 4; ++r) {
            const int o = ob * 16 + orow + r;
            f32x4 st;
            st[0] = acc[0][ob][r] + bv[r];
            st[1] = acc[1][ob][r] + bv[r];
            st[2] = acc[2][ob][r] + bv[r];
            st[3] = acc[3][ob][r] + bv[r];
            float* op = out + (((size_t)b * OC + o) * HH + h) * WW + wv * 64 + 4 * g16;
            __builtin_nontemporal_store(st, (f32x4*)op);
        }
    }
}

// ================= fallback (R1 fp32 path, tiny ws) ======================
__global__ void fovconv_transpose_w(const float* __restrict__ w,
                                    float* __restrict__ wT) {
    int i = blockIdx.x * 256 + threadIdx.x;
    const int N = OC * INC * KS * KS;
    if (i < N) {
        int o  = i / (INC * KS * KS);
        int ct = i % (INC * KS * KS);
        wT[ct * OC + o] = w[i];
    }
}

__global__ void __launch_bounds__(256)
fovconv_main(const float* __restrict__ x, const float* __restrict__ wT,
             const float* __restrict__ bias, float* __restrict__ out) {
    const int wpix = threadIdx.x;
    const int h    = blockIdx.x & (HH - 1);
    const int b    = blockIdx.x >> 8;
    float acc[OC];
#pragma unroll
    for (int o = 0; o < OC; ++o) acc[o] = 0.f;
    const float* xbp = x + (size_t)b * INC * HH * WW;
    for (int k = 0; k < KS; ++k) {
        const int dy = k - 5;
        for (int l = 0; l < KS; ++l) {
            const int dx = l - 5;
            const int d  = max(abs(dy), abs(dx));
            const int scale = (d <= 1) ? 1 : (d == 2 ? 3 : (d == 3 ? 5 : 7));
            const int sy = min(max(h + dy * scale, 0), HH - 1);
            const int sx = min(max(wpix + dx * scale, 0), WW - 1);
            const int base = sy * WW + sx;
            const int t = k * KS + l;
#pragma unroll
            for (int c = 0; c < INC; ++c) {
                const float xv = xbp[c * (HH * WW) + base];
                const float* wp = wT + (c * (KS * KS) + t) * OC;
#pragma unroll
                for (int o = 0; o < OC; ++o)
                    acc[o] = fmaf(xv, wp[o], acc[o]);
            }
        }
    }
    float* op = out + (((size_t)b * OC) * HH + h) * WW + wpix;
#pragma unroll
    for (int o = 0; o < OC; ++o)
        op[(size_t)o * HH * WW] = acc[o] + bias[o];
}

extern "C" void kernel_launch(void* const* d_in, const int* in_sizes, int n_in,
                              void* d_out, int out_size, void* d_ws, size_t ws_size,
                              hipStream_t stream) {
    const float* x    = (const float*)d_in[0];
    const float* wgt  = (const float*)d_in[1];
    const float* bias = (const float*)d_in[2];
    float* out = (float*)d_out;

    const size_t xs_bytes = (size_t)BB * INC * PH * PW * 2;   // 4,005,888
    const size_t wf_bytes = (size_t)NKC * 4 * 64 * 8 * 2;     //    49,152

    if (ws_size >= xs_bytes + wf_bytes) {
        u16* xsb = (u16*)d_ws;
        u16* wf  = (u16*)((char*)d_ws + xs_bytes);
        // 96 wfrag blocks + 1960 XCD-aligned pad blocks (2 rows each)
        prep_fused<<<96 + 245 * 8, 256, 0, stream>>>(x, wgt, xsb, wf);
        fov_lds<<<BB * HH, 256, 0, stream>>>(xsb, wf, bias, out);
    } else {
        float* wT = (float*)d_ws;
        const int NW = OC * INC * KS * KS;
        fovconv_transpose_w<<<(NW + 255) / 256, 256, 0, stream>>>(wgt, wT);
        fovconv_main<<<BB * HH, 256, 0, stream>>>(x, wT, bias, out);
    }
}